// Round 6
// baseline (559.942 us; speedup 1.0000x reference)
//
#include <hip/hip_runtime.h>
#include <float.h>

#define BB 16
#define NN 4096
#define CC 64
#define KNN 32
#define NPART 4
#define PSZ 1024   // NN / NPART
#define NQ 65536   // BB * NN

// ===========================================================================
// KNN, reference arithmetic VARIANT V2 (verified bit-compatible in R4):
//   dot = fma(z,z', fma(y,y', x*x'));  xx = ((x*x + y*y) + z*z)  [rn, no fma]
//   pd  = ((dot+dot) - xx_q) - xx_c    [left-assoc rn]
// Largest pd = nearest.
//
// R6: R5's select ran at 2.3x its VALU floor with VGPR_Count=24 — impossible
// for a 32-float heap => compiler demoted heap[] out of registers. Heap is
// now 32 NAMED scalars + macro-generated med3 chain (no indexable array),
// __launch_bounds__(256,2) to give the allocator a 256-VGPR budget.
// ===========================================================================

// h_t = med3(pd, h_t, h_{t-1}), t = 31..1 (each reads not-yet-updated t-1)
#define INS_CHAIN \
  h31=M3(h31,h30); h30=M3(h30,h29); h29=M3(h29,h28); h28=M3(h28,h27); \
  h27=M3(h27,h26); h26=M3(h26,h25); h25=M3(h25,h24); h24=M3(h24,h23); \
  h23=M3(h23,h22); h22=M3(h22,h21); h21=M3(h21,h20); h20=M3(h20,h19); \
  h19=M3(h19,h18); h18=M3(h18,h17); h17=M3(h17,h16); h16=M3(h16,h15); \
  h15=M3(h15,h14); h14=M3(h14,h13); h13=M3(h13,h12); h12=M3(h12,h11); \
  h11=M3(h11,h10); h10=M3(h10,h09); h09=M3(h09,h08); h08=M3(h08,h07); \
  h07=M3(h07,h06); h06=M3(h06,h05); h05=M3(h05,h04); h04=M3(h04,h03); \
  h03=M3(h03,h02); h02=M3(h02,h01); h01=M3(h01,h00); h00=fmaxf(h00,pd);

#define H_DECL \
  float h00=-FLT_MAX,h01=-FLT_MAX,h02=-FLT_MAX,h03=-FLT_MAX, \
        h04=-FLT_MAX,h05=-FLT_MAX,h06=-FLT_MAX,h07=-FLT_MAX, \
        h08=-FLT_MAX,h09=-FLT_MAX,h10=-FLT_MAX,h11=-FLT_MAX, \
        h12=-FLT_MAX,h13=-FLT_MAX,h14=-FLT_MAX,h15=-FLT_MAX, \
        h16=-FLT_MAX,h17=-FLT_MAX,h18=-FLT_MAX,h19=-FLT_MAX, \
        h20=-FLT_MAX,h21=-FLT_MAX,h22=-FLT_MAX,h23=-FLT_MAX, \
        h24=-FLT_MAX,h25=-FLT_MAX,h26=-FLT_MAX,h27=-FLT_MAX, \
        h28=-FLT_MAX,h29=-FLT_MAX,h30=-FLT_MAX,h31=-FLT_MAX;

// --------------------------------------------------------------------------
// A: grid 1024 = (b<<6)|(g<<2)|p, 256 thr = 256 queries. LDS = 16KB partition.
// --------------------------------------------------------------------------
__global__ __launch_bounds__(256, 2) void knn_select_kernel(
        const float* __restrict__ xyz, float* __restrict__ val_buf) {
#pragma clang fp contract(off)
    __shared__ float4 pts[PSZ];  // 16 KB: x,y,z,xx
    const int tid = threadIdx.x;
    const int blk = blockIdx.x;
    const int p = blk & 3;
    const int g = (blk >> 2) & 15;
    const int b = blk >> 6;
    const float* xb = xyz + (size_t)b * (3 * NN);

    for (int j = tid; j < PSZ; j += 256) {
        int i = (p << 10) | j;
        float x = xb[i], y = xb[NN + i], z = xb[2 * NN + i];
        float xx = ((x * x) + (y * y)) + (z * z);  // rn (contract off)
        pts[j] = make_float4(x, y, z, xx);
    }
    const int q = (g << 8) | tid;  // query within batch
    const float qx = xb[q], qy = xb[NN + q], qz = xb[2 * NN + q];
    const float qxx = ((qx * qx) + (qy * qy)) + (qz * qz);
    __syncthreads();

    H_DECL
#define M3(a, b) __builtin_amdgcn_fmed3f(pd, a, b)
    for (int j = 0; j < PSZ; ++j) {
        float4 cp = pts[j];
        float dot = __builtin_fmaf(qz, cp.z, __builtin_fmaf(qy, cp.y, qx * cp.x));
        float pd = ((dot + dot) - qxx) - cp.w;
        INS_CHAIN
    }
#undef M3

    const int qg = (b << 12) | q;  // global query
    float* vp = val_buf + (size_t)(p * KNN) * NQ + qg;
#define ST(t, ht) vp[(size_t)(t) * NQ] = ht;
    ST(0,h00) ST(1,h01) ST(2,h02) ST(3,h03) ST(4,h04) ST(5,h05) ST(6,h06)
    ST(7,h07) ST(8,h08) ST(9,h09) ST(10,h10) ST(11,h11) ST(12,h12) ST(13,h13)
    ST(14,h14) ST(15,h15) ST(16,h16) ST(17,h17) ST(18,h18) ST(19,h19)
    ST(20,h20) ST(21,h21) ST(22,h22) ST(23,h23) ST(24,h24) ST(25,h25)
    ST(26,h26) ST(27,h27) ST(28,h28) ST(29,h29) ST(30,h30) ST(31,h31)
#undef ST
}

// --------------------------------------------------------------------------
// B: one thread per query; 64-thr blocks; lists staged to LDS (pad 129).
// --------------------------------------------------------------------------
__global__ __launch_bounds__(64) void knn_merge_kernel(
        const float* __restrict__ val_buf, float* __restrict__ T_buf,
        int* __restrict__ pack_buf) {
    __shared__ float lv[64 * 129];  // 33 KB
    const int tid = threadIdx.x;
    const int qg = blockIdx.x * 64 + tid;
    float* my = lv + tid * 129;
    for (int t = 0; t < 128; ++t) my[t] = val_buf[(size_t)t * NQ + qg];

    int i0 = 0, i1 = 0, i2 = 0, i3 = 0;
    float T = -FLT_MAX;
    for (int s = 0; s < 32; ++s) {
        float v0 = (i0 < 32) ? my[i0] : -FLT_MAX;
        float v1 = (i1 < 32) ? my[32 + i1] : -FLT_MAX;
        float v2 = (i2 < 32) ? my[64 + i2] : -FLT_MAX;
        float v3 = (i3 < 32) ? my[96 + i3] : -FLT_MAX;
        float best = v0; int bp = 0;
        if (v1 > best) { best = v1; bp = 1; }   // strict: ties keep lower p
        if (v2 > best) { best = v2; bp = 2; }
        if (v3 > best) { best = v3; bp = 3; }
        T = best;
        i0 += (bp == 0); i1 += (bp == 1); i2 += (bp == 2); i3 += (bp == 3);
    }
    int s0 = 0, s1 = 0, s2 = 0, s3 = 0;
    for (int j = 0; j < 32; ++j) {
        s0 += (my[j] > T); s1 += (my[32 + j] > T);
        s2 += (my[64 + j] > T); s3 += (my[96 + j] > T);
    }
    T_buf[qg] = T;
    int base = 0;
    pack_buf[qg * 4 + 0] = base | (s0 << 8) | (i0 << 16); base += i0;
    pack_buf[qg * 4 + 1] = base | (s1 << 8) | (i1 << 16); base += i1;
    pack_buf[qg * 4 + 2] = base | (s2 << 8) | (i2 << 16); base += i2;
    pack_buf[qg * 4 + 3] = base | (s3 << 8) | (i3 << 16);
}

// --------------------------------------------------------------------------
// C: same shape as A; re-scan with T, emit batch-local indices.
// --------------------------------------------------------------------------
__global__ __launch_bounds__(256) void knn_emit_kernel(
        const float* __restrict__ xyz, const float* __restrict__ T_buf,
        const int* __restrict__ pack_buf, int* __restrict__ idx_out) {
#pragma clang fp contract(off)
    __shared__ float4 pts[PSZ];
    const int tid = threadIdx.x;
    const int blk = blockIdx.x;
    const int p = blk & 3;
    const int g = (blk >> 2) & 15;
    const int b = blk >> 6;
    const float* xb = xyz + (size_t)b * (3 * NN);

    for (int j = tid; j < PSZ; j += 256) {
        int i = (p << 10) | j;
        float x = xb[i], y = xb[NN + i], z = xb[2 * NN + i];
        float xx = ((x * x) + (y * y)) + (z * z);
        pts[j] = make_float4(x, y, z, xx);
    }
    const int q = (g << 8) | tid;
    const float qx = xb[q], qy = xb[NN + q], qz = xb[2 * NN + q];
    const float qxx = ((qx * qx) + (qy * qy)) + (qz * qz);
    __syncthreads();

    const int qg = (b << 12) | q;
    const float T = T_buf[qg];
    const int pk = pack_buf[qg * 4 + p];
    int slot = pk & 255;
    const int sp = (pk >> 8) & 255;
    const int np = (pk >> 16) & 255;
    int tie_slot = slot + sp;
    const int tie_end = slot + np;
    int* outp = idx_out + (size_t)qg * KNN;

    for (int j = 0; j < PSZ; ++j) {
        float4 cp = pts[j];
        float dot = __builtin_fmaf(qz, cp.z, __builtin_fmaf(qy, cp.y, qx * cp.x));
        float pd = ((dot + dot) - qxx) - cp.w;
        if (pd > T) {
            outp[slot++] = (p << 10) | j;
        } else if (pd == T && tie_slot < tie_end) {
            outp[tie_slot++] = (p << 10) | j;
        }
    }
}

// --------------------------------------------------------------------------
// gather: one wave per query, lane = channel; fp64 sigma accumulation.
// --------------------------------------------------------------------------
__global__ __launch_bounds__(256) void gather_minmax_kernel(
        const float* __restrict__ feats, const int* __restrict__ idx_in,
        float* __restrict__ mx_buf, float* __restrict__ mn_buf,
        double* __restrict__ partials) {
    const int tid = threadIdx.x;
    const int w = tid >> 6;
    const int lane = tid & 63;
    const int q = blockIdx.x * 4 + w;
    const int b = q >> 12;
    const float* fb = feats + (size_t)b * (NN * CC);
    const float center = feats[(size_t)q * CC + lane];
    const int* ip = idx_in + (size_t)q * KNN;

    float mx = -FLT_MAX, mn = FLT_MAX;
    double ss = 0.0;
#pragma unroll 4
    for (int k = 0; k < KNN; ++k) {
        int nb = ip[k];
        float v = fb[(size_t)nb * CC + lane];
        float off = v - center;
        mx = fmaxf(mx, off);
        mn = fminf(mn, off);
        double od = (double)off;
        ss = fma(od, od, ss);
    }
    mx_buf[(size_t)q * CC + lane] = mx;
    mn_buf[(size_t)q * CC + lane] = mn;

#pragma unroll
    for (int o = 32; o >= 1; o >>= 1) ss += __shfl_down(ss, o, 64);
    __shared__ double wsum[4];
    if (lane == 0) wsum[w] = ss;
    __syncthreads();
    if (tid == 0) partials[blockIdx.x] = (wsum[0] + wsum[1]) + (wsum[2] + wsum[3]);
}

__global__ __launch_bounds__(256) void sigma_kernel(const double* __restrict__ partials,
                                                    float* __restrict__ sigma) {
    __shared__ double red[256];
    double s = 0.0;
    for (int i = threadIdx.x; i < 16384; i += 256) s += partials[i];
    red[threadIdx.x] = s;
    __syncthreads();
    for (int o = 128; o >= 1; o >>= 1) {
        if (threadIdx.x < o) red[threadIdx.x] += red[threadIdx.x + o];
        __syncthreads();
    }
    if (threadIdx.x == 0) sigma[0] = (float)(red[0] * (1.0 / 134217728.0));
}

__global__ __launch_bounds__(256) void finalize_kernel(
        const float* __restrict__ mx_buf, const float* __restrict__ mn_buf,
        const float* __restrict__ alpha, const float* __restrict__ beta,
        const float* __restrict__ sigma, float* __restrict__ out) {
#pragma clang fp contract(off)
    const int e = blockIdx.x * 256 + threadIdx.x;
    const int c = e & (CC - 1);
    const float s = sigma[0] + 1e-5f;
    const float a = alpha[c];
    const float bt = beta[c];
    const float off = (a >= 0.f) ? mx_buf[e] : mn_buf[e];
    const float t = off / s;
    out[e] = (t * a) + bt;
}

extern "C" void kernel_launch(void* const* d_in, const int* in_sizes, int n_in,
                              void* d_out, int out_size, void* d_ws, size_t ws_size,
                              hipStream_t stream) {
    (void)in_sizes; (void)n_in; (void)out_size; (void)ws_size;
    const float* xyz   = (const float*)d_in[0];  // [16,3,4096]
    const float* feats = (const float*)d_in[1];  // [16,4096,64]
    const float* alpha = (const float*)d_in[2];  // [64]
    const float* beta  = (const float*)d_in[3];  // [64]
    float* out = (float*)d_out;                  // [16,4096,64]

    char* ws = (char*)d_ws;
    // Layout (aliased — val_buf is dead before gather writes mx/mn):
    int*    idx_buf  = (int*)ws;                     // [0, 8MB)
    float*  val_buf  = (float*)(ws + 8388608);       // [8MB, 40MB)  65536*128*4
    float*  mx_buf   = (float*)(ws + 8388608);       // alias  [8MB, 24MB)
    float*  mn_buf   = (float*)(ws + 25165824);      // alias  [24MB, 40MB)
    float*  T_buf    = (float*)(ws + 41943040);      // [40MB, +256KB)
    int*    pack_buf = (int*)(ws + 42205184);        // [+1MB)
    double* partials = (double*)(ws + 43253760);     // 16384*8 = 128KB
    float*  sigma    = (float*)(ws + 43384832);

    knn_select_kernel<<<BB * 16 * NPART, 256, 0, stream>>>(xyz, val_buf);
    knn_merge_kernel<<<NQ / 64, 64, 0, stream>>>(val_buf, T_buf, pack_buf);
    knn_emit_kernel<<<BB * 16 * NPART, 256, 0, stream>>>(xyz, T_buf, pack_buf, idx_buf);
    gather_minmax_kernel<<<NQ / 4, 256, 0, stream>>>(feats, idx_buf, mx_buf,
                                                     mn_buf, partials);
    sigma_kernel<<<1, 256, 0, stream>>>(partials, sigma);
    finalize_kernel<<<(NQ * CC) / 256, 256, 0, stream>>>(mx_buf, mn_buf, alpha,
                                                         beta, sigma, out);
}

// Round 7
// 559.478 us; speedup vs baseline: 1.0008x; 1.0008x over previous
//
#include <hip/hip_runtime.h>
#include <float.h>

#define BB 16
#define NN 4096
#define CC 64
#define KNN 32
#define NPART 4
#define PSZ 1024   // NN / NPART
#define NQ 65536   // BB * NN

// ===========================================================================
// KNN, reference arithmetic VARIANT V2 (verified bit-compatible in R4):
//   dot = fma(z,z', fma(y,y', x*x'));  xx = ((x*x + y*y) + z*z)  [rn, no fma]
//   pd  = ((dot+dot) - xx_q) - xx_c    [left-assoc rn]
// Largest pd = nearest.
//
// R7: R5/R6 select ran at ~84 issue-slots/iter vs ~40 in source with
// VGPR_Count=24 — theory: compiler holds the 32-slot heap in AGPRs (unified
// file) and pays v_accvgpr_read/write around every med3. Fix: inline-asm the
// insert chain (v_med3_f32 with "+v" constraints) so the heap MUST live in
// arch VGPRs. Select kernel only; everything else identical to R6.
// ===========================================================================

// h_t = med3(pd, h_t, h_{t-1}), t = 31..1 (reads pre-update h_{t-1}),
// then h00 = max(h00, pd). Asm pins all operands to arch VGPRs.
#define INS1(ht, hm) asm("v_med3_f32 %0, %1, %0, %2" : "+v"(ht) : "v"(pd), "v"(hm));
#define INS_CHAIN \
  INS1(h31,h30) INS1(h30,h29) INS1(h29,h28) INS1(h28,h27) \
  INS1(h27,h26) INS1(h26,h25) INS1(h25,h24) INS1(h24,h23) \
  INS1(h23,h22) INS1(h22,h21) INS1(h21,h20) INS1(h20,h19) \
  INS1(h19,h18) INS1(h18,h17) INS1(h17,h16) INS1(h16,h15) \
  INS1(h15,h14) INS1(h14,h13) INS1(h13,h12) INS1(h12,h11) \
  INS1(h11,h10) INS1(h10,h09) INS1(h09,h08) INS1(h08,h07) \
  INS1(h07,h06) INS1(h06,h05) INS1(h05,h04) INS1(h04,h03) \
  INS1(h03,h02) INS1(h02,h01) INS1(h01,h00) \
  asm("v_max_f32 %0, %1, %0" : "+v"(h00) : "v"(pd));

#define H_DECL \
  float h00=-FLT_MAX,h01=-FLT_MAX,h02=-FLT_MAX,h03=-FLT_MAX, \
        h04=-FLT_MAX,h05=-FLT_MAX,h06=-FLT_MAX,h07=-FLT_MAX, \
        h08=-FLT_MAX,h09=-FLT_MAX,h10=-FLT_MAX,h11=-FLT_MAX, \
        h12=-FLT_MAX,h13=-FLT_MAX,h14=-FLT_MAX,h15=-FLT_MAX, \
        h16=-FLT_MAX,h17=-FLT_MAX,h18=-FLT_MAX,h19=-FLT_MAX, \
        h20=-FLT_MAX,h21=-FLT_MAX,h22=-FLT_MAX,h23=-FLT_MAX, \
        h24=-FLT_MAX,h25=-FLT_MAX,h26=-FLT_MAX,h27=-FLT_MAX, \
        h28=-FLT_MAX,h29=-FLT_MAX,h30=-FLT_MAX,h31=-FLT_MAX;

// --------------------------------------------------------------------------
// A: grid 1024 = (b<<6)|(g<<2)|p, 256 thr = 256 queries. LDS = 16KB partition.
// --------------------------------------------------------------------------
__global__ __launch_bounds__(256, 2) void knn_select_kernel(
        const float* __restrict__ xyz, float* __restrict__ val_buf) {
#pragma clang fp contract(off)
    __shared__ float4 pts[PSZ];  // 16 KB: x,y,z,xx
    const int tid = threadIdx.x;
    const int blk = blockIdx.x;
    const int p = blk & 3;
    const int g = (blk >> 2) & 15;
    const int b = blk >> 6;
    const float* xb = xyz + (size_t)b * (3 * NN);

    for (int j = tid; j < PSZ; j += 256) {
        int i = (p << 10) | j;
        float x = xb[i], y = xb[NN + i], z = xb[2 * NN + i];
        float xx = ((x * x) + (y * y)) + (z * z);  // rn (contract off)
        pts[j] = make_float4(x, y, z, xx);
    }
    const int q = (g << 8) | tid;  // query within batch
    const float qx = xb[q], qy = xb[NN + q], qz = xb[2 * NN + q];
    const float qxx = ((qx * qx) + (qy * qy)) + (qz * qz);
    __syncthreads();

    H_DECL
#pragma unroll 2
    for (int j = 0; j < PSZ; ++j) {
        float4 cp = pts[j];
        float dot = __builtin_fmaf(qz, cp.z, __builtin_fmaf(qy, cp.y, qx * cp.x));
        float pd = ((dot + dot) - qxx) - cp.w;
        INS_CHAIN
    }

    const int qg = (b << 12) | q;  // global query
    float* vp = val_buf + (size_t)(p * KNN) * NQ + qg;
#define ST(t, ht) vp[(size_t)(t) * NQ] = ht;
    ST(0,h00) ST(1,h01) ST(2,h02) ST(3,h03) ST(4,h04) ST(5,h05) ST(6,h06)
    ST(7,h07) ST(8,h08) ST(9,h09) ST(10,h10) ST(11,h11) ST(12,h12) ST(13,h13)
    ST(14,h14) ST(15,h15) ST(16,h16) ST(17,h17) ST(18,h18) ST(19,h19)
    ST(20,h20) ST(21,h21) ST(22,h22) ST(23,h23) ST(24,h24) ST(25,h25)
    ST(26,h26) ST(27,h27) ST(28,h28) ST(29,h29) ST(30,h30) ST(31,h31)
#undef ST
}

// --------------------------------------------------------------------------
// B: one thread per query; 64-thr blocks; lists staged to LDS (pad 129).
// --------------------------------------------------------------------------
__global__ __launch_bounds__(64) void knn_merge_kernel(
        const float* __restrict__ val_buf, float* __restrict__ T_buf,
        int* __restrict__ pack_buf) {
    __shared__ float lv[64 * 129];  // 33 KB
    const int tid = threadIdx.x;
    const int qg = blockIdx.x * 64 + tid;
    float* my = lv + tid * 129;
    for (int t = 0; t < 128; ++t) my[t] = val_buf[(size_t)t * NQ + qg];

    int i0 = 0, i1 = 0, i2 = 0, i3 = 0;
    float T = -FLT_MAX;
    for (int s = 0; s < 32; ++s) {
        float v0 = (i0 < 32) ? my[i0] : -FLT_MAX;
        float v1 = (i1 < 32) ? my[32 + i1] : -FLT_MAX;
        float v2 = (i2 < 32) ? my[64 + i2] : -FLT_MAX;
        float v3 = (i3 < 32) ? my[96 + i3] : -FLT_MAX;
        float best = v0; int bp = 0;
        if (v1 > best) { best = v1; bp = 1; }   // strict: ties keep lower p
        if (v2 > best) { best = v2; bp = 2; }
        if (v3 > best) { best = v3; bp = 3; }
        T = best;
        i0 += (bp == 0); i1 += (bp == 1); i2 += (bp == 2); i3 += (bp == 3);
    }
    int s0 = 0, s1 = 0, s2 = 0, s3 = 0;
    for (int j = 0; j < 32; ++j) {
        s0 += (my[j] > T); s1 += (my[32 + j] > T);
        s2 += (my[64 + j] > T); s3 += (my[96 + j] > T);
    }
    T_buf[qg] = T;
    int base = 0;
    pack_buf[qg * 4 + 0] = base | (s0 << 8) | (i0 << 16); base += i0;
    pack_buf[qg * 4 + 1] = base | (s1 << 8) | (i1 << 16); base += i1;
    pack_buf[qg * 4 + 2] = base | (s2 << 8) | (i2 << 16); base += i2;
    pack_buf[qg * 4 + 3] = base | (s3 << 8) | (i3 << 16);
}

// --------------------------------------------------------------------------
// C: same shape as A; re-scan with T, emit batch-local indices.
// --------------------------------------------------------------------------
__global__ __launch_bounds__(256) void knn_emit_kernel(
        const float* __restrict__ xyz, const float* __restrict__ T_buf,
        const int* __restrict__ pack_buf, int* __restrict__ idx_out) {
#pragma clang fp contract(off)
    __shared__ float4 pts[PSZ];
    const int tid = threadIdx.x;
    const int blk = blockIdx.x;
    const int p = blk & 3;
    const int g = (blk >> 2) & 15;
    const int b = blk >> 6;
    const float* xb = xyz + (size_t)b * (3 * NN);

    for (int j = tid; j < PSZ; j += 256) {
        int i = (p << 10) | j;
        float x = xb[i], y = xb[NN + i], z = xb[2 * NN + i];
        float xx = ((x * x) + (y * y)) + (z * z);
        pts[j] = make_float4(x, y, z, xx);
    }
    const int q = (g << 8) | tid;
    const float qx = xb[q], qy = xb[NN + q], qz = xb[2 * NN + q];
    const float qxx = ((qx * qx) + (qy * qy)) + (qz * qz);
    __syncthreads();

    const int qg = (b << 12) | q;
    const float T = T_buf[qg];
    const int pk = pack_buf[qg * 4 + p];
    int slot = pk & 255;
    const int sp = (pk >> 8) & 255;
    const int np = (pk >> 16) & 255;
    int tie_slot = slot + sp;
    const int tie_end = slot + np;
    int* outp = idx_out + (size_t)qg * KNN;

    for (int j = 0; j < PSZ; ++j) {
        float4 cp = pts[j];
        float dot = __builtin_fmaf(qz, cp.z, __builtin_fmaf(qy, cp.y, qx * cp.x));
        float pd = ((dot + dot) - qxx) - cp.w;
        if (pd > T) {
            outp[slot++] = (p << 10) | j;
        } else if (pd == T && tie_slot < tie_end) {
            outp[tie_slot++] = (p << 10) | j;
        }
    }
}

// --------------------------------------------------------------------------
// gather: one wave per query, lane = channel; fp64 sigma accumulation.
// --------------------------------------------------------------------------
__global__ __launch_bounds__(256) void gather_minmax_kernel(
        const float* __restrict__ feats, const int* __restrict__ idx_in,
        float* __restrict__ mx_buf, float* __restrict__ mn_buf,
        double* __restrict__ partials) {
    const int tid = threadIdx.x;
    const int w = tid >> 6;
    const int lane = tid & 63;
    const int q = blockIdx.x * 4 + w;
    const int b = q >> 12;
    const float* fb = feats + (size_t)b * (NN * CC);
    const float center = feats[(size_t)q * CC + lane];
    const int* ip = idx_in + (size_t)q * KNN;

    float mx = -FLT_MAX, mn = FLT_MAX;
    double ss = 0.0;
#pragma unroll 4
    for (int k = 0; k < KNN; ++k) {
        int nb = ip[k];
        float v = fb[(size_t)nb * CC + lane];
        float off = v - center;
        mx = fmaxf(mx, off);
        mn = fminf(mn, off);
        double od = (double)off;
        ss = fma(od, od, ss);
    }
    mx_buf[(size_t)q * CC + lane] = mx;
    mn_buf[(size_t)q * CC + lane] = mn;

#pragma unroll
    for (int o = 32; o >= 1; o >>= 1) ss += __shfl_down(ss, o, 64);
    __shared__ double wsum[4];
    if (lane == 0) wsum[w] = ss;
    __syncthreads();
    if (tid == 0) partials[blockIdx.x] = (wsum[0] + wsum[1]) + (wsum[2] + wsum[3]);
}

__global__ __launch_bounds__(256) void sigma_kernel(const double* __restrict__ partials,
                                                    float* __restrict__ sigma) {
    __shared__ double red[256];
    double s = 0.0;
    for (int i = threadIdx.x; i < 16384; i += 256) s += partials[i];
    red[threadIdx.x] = s;
    __syncthreads();
    for (int o = 128; o >= 1; o >>= 1) {
        if (threadIdx.x < o) red[threadIdx.x] += red[threadIdx.x + o];
        __syncthreads();
    }
    if (threadIdx.x == 0) sigma[0] = (float)(red[0] * (1.0 / 134217728.0));
}

__global__ __launch_bounds__(256) void finalize_kernel(
        const float* __restrict__ mx_buf, const float* __restrict__ mn_buf,
        const float* __restrict__ alpha, const float* __restrict__ beta,
        const float* __restrict__ sigma, float* __restrict__ out) {
#pragma clang fp contract(off)
    const int e = blockIdx.x * 256 + threadIdx.x;
    const int c = e & (CC - 1);
    const float s = sigma[0] + 1e-5f;
    const float a = alpha[c];
    const float bt = beta[c];
    const float off = (a >= 0.f) ? mx_buf[e] : mn_buf[e];
    const float t = off / s;
    out[e] = (t * a) + bt;
}

extern "C" void kernel_launch(void* const* d_in, const int* in_sizes, int n_in,
                              void* d_out, int out_size, void* d_ws, size_t ws_size,
                              hipStream_t stream) {
    (void)in_sizes; (void)n_in; (void)out_size; (void)ws_size;
    const float* xyz   = (const float*)d_in[0];  // [16,3,4096]
    const float* feats = (const float*)d_in[1];  // [16,4096,64]
    const float* alpha = (const float*)d_in[2];  // [64]
    const float* beta  = (const float*)d_in[3];  // [64]
    float* out = (float*)d_out;                  // [16,4096,64]

    char* ws = (char*)d_ws;
    // Layout (aliased — val_buf is dead before gather writes mx/mn):
    int*    idx_buf  = (int*)ws;                     // [0, 8MB)
    float*  val_buf  = (float*)(ws + 8388608);       // [8MB, 40MB)  65536*128*4
    float*  mx_buf   = (float*)(ws + 8388608);       // alias  [8MB, 24MB)
    float*  mn_buf   = (float*)(ws + 25165824);      // alias  [24MB, 40MB)
    float*  T_buf    = (float*)(ws + 41943040);      // [40MB, +256KB)
    int*    pack_buf = (int*)(ws + 42205184);        // [+1MB)
    double* partials = (double*)(ws + 43253760);     // 16384*8 = 128KB
    float*  sigma    = (float*)(ws + 43384832);

    knn_select_kernel<<<BB * 16 * NPART, 256, 0, stream>>>(xyz, val_buf);
    knn_merge_kernel<<<NQ / 64, 64, 0, stream>>>(val_buf, T_buf, pack_buf);
    knn_emit_kernel<<<BB * 16 * NPART, 256, 0, stream>>>(xyz, T_buf, pack_buf, idx_buf);
    gather_minmax_kernel<<<NQ / 4, 256, 0, stream>>>(feats, idx_buf, mx_buf,
                                                     mn_buf, partials);
    sigma_kernel<<<1, 256, 0, stream>>>(partials, sigma);
    finalize_kernel<<<(NQ * CC) / 256, 256, 0, stream>>>(mx_buf, mn_buf, alpha,
                                                         beta, sigma, out);
}